// Round 3
// baseline (98.208 us; speedup 1.0000x reference)
//
#include <hip/hip_runtime.h>
#include <hip/hip_bf16.h>

#define S_   8
#define N_   1024
#define KG_  16
#define MW_  64
#define CI_  128
#define CO_  256

typedef __attribute__((ext_vector_type(8))) short bf16x8;
typedef __attribute__((ext_vector_type(4))) float f32x4;

// ---------------------------------------------------------------------------
// Fused: W fp32->bf16 convert + circular sliding-window sums (bf16 out).
// win[s][t][c] = sum_{m<64} x[s][(t+m)%N][c]
// ---------------------------------------------------------------------------
__global__ __launch_bounds__(256) void win_kernel(const float* __restrict__ x,
                                                  const float* __restrict__ W,
                                                  __hip_bfloat16* __restrict__ win,
                                                  __hip_bfloat16* __restrict__ Wb) {
    __shared__ float lds[96][CI_];           // 48 KB
    const int b   = blockIdx.x;              // 0..255
    const int tid = threadIdx.x;

    // --- W conversion: 8 elems per thread (65536 threads x 8 = 524288) ---
    {
        const int wi = (b * 256 + tid) * 8;
        const float4 v0 = *(const float4*)&W[wi];
        const float4 v1 = *(const float4*)&W[wi + 4];
        union { unsigned short u[8]; uint4 v; } o;
        __hip_bfloat16 h;
        h = __float2bfloat16(v0.x); o.u[0] = *(unsigned short*)&h;
        h = __float2bfloat16(v0.y); o.u[1] = *(unsigned short*)&h;
        h = __float2bfloat16(v0.z); o.u[2] = *(unsigned short*)&h;
        h = __float2bfloat16(v0.w); o.u[3] = *(unsigned short*)&h;
        h = __float2bfloat16(v1.x); o.u[4] = *(unsigned short*)&h;
        h = __float2bfloat16(v1.y); o.u[5] = *(unsigned short*)&h;
        h = __float2bfloat16(v1.z); o.u[6] = *(unsigned short*)&h;
        h = __float2bfloat16(v1.w); o.u[7] = *(unsigned short*)&h;
        *(uint4*)&Wb[wi] = o.v;
    }

    // --- sliding window ---
    const int s   = b >> 5;
    const int t0  = (b & 31) << 5;           // 32 t's per block
    const float* xs = x + (size_t)s * N_ * CI_;

    for (int e = tid * 4; e < 96 * CI_; e += 256 * 4) {
        const int r = e >> 7;
        const int c = e & (CI_ - 1);
        *(float4*)&lds[r][c] = *(const float4*)&xs[((t0 + r) & (N_ - 1)) * CI_ + c];
    }
    __syncthreads();

    const int c  = tid & (CI_ - 1);
    const int tb = (tid >> 7) << 4;          // 0 or 16
    float s0 = 0.f, s1 = 0.f, s2 = 0.f, s3 = 0.f;
    #pragma unroll
    for (int m = 0; m < MW_; m += 4) {
        s0 += lds[tb + m + 0][c];
        s1 += lds[tb + m + 1][c];
        s2 += lds[tb + m + 2][c];
        s3 += lds[tb + m + 3][c];
    }
    float w = (s0 + s1) + (s2 + s3);
    __hip_bfloat16* wo = win + (size_t)s * N_ * CI_;
    wo[(t0 + tb) * CI_ + c] = __float2bfloat16(w);
    #pragma unroll
    for (int t = 1; t < 16; ++t) {
        w += lds[tb + t - 1 + MW_][c] - lds[tb + t - 1][c];
        wo[(t0 + tb + t) * CI_ + c] = __float2bfloat16(w);
    }
}

// ---------------------------------------------------------------------------
// out[s,n,o] = sum_{g,c} win[s,(n+64g)%N,c] * W[g,o,c]
// MFMA GEMM, M=8192, N=256, K=2048.  Block tile 128x64, BK=64 (32 K-steps),
// grid (64,4)=256 blocks, 4 waves, wave tile 64x32 (4x2 frags 16x16x32 bf16).
// LDS 48KB double-buffered.  Counted-vmcnt pipeline (T3/T4): raw s_barrier +
// "s_waitcnt vmcnt(6)" so the 6 just-issued next-tile global_load_lds per
// wave stay in flight across the barrier (no per-step drain).
// Swizzle: LDS row = 128B (8 x 16B slots), phys slot = logical ^ (row&7);
// applied on the pre-swizzled global source (linear LDS dest) and on ds_read.
// ---------------------------------------------------------------------------
#define BKE  64                 // K elems per step
#define AST  (128 * BKE)        // 8192 elems = 16 KB
#define BST  (64  * BKE)        // 4096 elems =  8 KB
#define KSTEPS 32

__global__ __launch_bounds__(256) void gemm_kernel(const __hip_bfloat16* __restrict__ winb,
                                                   const __hip_bfloat16* __restrict__ Wb,
                                                   float* __restrict__ out) {
    __shared__ __align__(16) unsigned short Alds[2 * AST];   // 32 KB
    __shared__ __align__(16) unsigned short Blds[2 * BST];   // 16 KB

    const int tid = threadIdx.x;
    const int l   = tid & 63;
    const int wv  = tid >> 6;
    const int s   = blockIdx.x >> 3;
    const int n0  = (blockIdx.x & 7) << 7;   // 128-row tile
    const int o0  = blockIdx.y << 6;         // 64-col tile

    const int wm = wv >> 1;                  // 0..1: 64-row half
    const int wn = wv & 1;                   // 0..1: 32-col half
    const int fr = l & 15;
    const int kq = l >> 4;                   // 0..3
    const int rl = l >> 3;                   // staging: row within 8-row chunk
    const int ps = l & 7;                    // staging: physical 16B slot

    const unsigned short* winp = (const unsigned short*)winb + (size_t)s * N_ * CI_;
    const unsigned short* Wp   = (const unsigned short*)Wb;

    f32x4 acc[4][2];
    #pragma unroll
    for (int i = 0; i < 4; ++i)
        #pragma unroll
        for (int j = 0; j < 2; ++j)
            acc[i][j] = f32x4{0.f, 0.f, 0.f, 0.f};

    // Stage tile t into buffer buf: A 16 chunks of 1KB, B 8 chunks; 6/wave.
    auto stage = [&](int t, int buf) {
        const int g  = t >> 1;
        const int ch = (t & 1) << 6;         // K half within the group
        unsigned short* Ab = &Alds[buf * AST];
        unsigned short* Bb = &Blds[buf * BST];
        #pragma unroll
        for (int q = 0; q < 4; ++q) {
            const int rb  = (wv * 4 + q) * 8;
            const int row = rb + rl;
            const int ss  = ps ^ (row & 7);
            const unsigned short* src =
                winp + (((n0 + (g << 6) + row) & (N_ - 1)) * CI_) + ch + ss * 8;
            __builtin_amdgcn_global_load_lds((const __attribute__((address_space(1))) void*)src,
                                             (__attribute__((address_space(3))) void*)(Ab + rb * BKE),
                                             16, 0, 0);
        }
        #pragma unroll
        for (int q = 0; q < 2; ++q) {
            const int rb  = (wv * 2 + q) * 8;
            const int row = rb + rl;
            const int ss  = ps ^ (row & 7);
            const unsigned short* src =
                Wp + ((g * CO_ + o0 + row) * CI_) + ch + ss * 8;
            __builtin_amdgcn_global_load_lds((const __attribute__((address_space(1))) void*)src,
                                             (__attribute__((address_space(3))) void*)(Bb + rb * BKE),
                                             16, 0, 0);
        }
    };

    stage(0, 0);                             // 6 loads in flight

    for (int t = 0; t < KSTEPS; ++t) {
        const int cur = t & 1;
        if (t < KSTEPS - 1) {
            stage(t + 1, cur ^ 1);           // +6 -> 12 in flight
            asm volatile("s_waitcnt vmcnt(6)" ::: "memory");   // tile t done
        } else {
            asm volatile("s_waitcnt vmcnt(0)" ::: "memory");
        }
        __builtin_amdgcn_sched_barrier(0);
        __builtin_amdgcn_s_barrier();        // buf[cur] ready for all waves

        const unsigned short* Ab = &Alds[cur * AST];
        const unsigned short* Bb = &Blds[cur * BST];
        #pragma unroll
        for (int ks = 0; ks < 2; ++ks) {
            const int sl = ks * 4 + kq;      // logical 16B slot 0..7
            bf16x8 af[4], bfg[2];
            #pragma unroll
            for (int i = 0; i < 4; ++i) {
                const int row = wm * 64 + i * 16 + fr;
                af[i] = *(const bf16x8*)&Ab[row * BKE + ((sl ^ (row & 7)) * 8)];
            }
            #pragma unroll
            for (int j = 0; j < 2; ++j) {
                const int col = wn * 32 + j * 16 + fr;
                bfg[j] = *(const bf16x8*)&Bb[col * BKE + ((sl ^ (col & 7)) * 8)];
            }
            #pragma unroll
            for (int i = 0; i < 4; ++i)
                #pragma unroll
                for (int j = 0; j < 2; ++j)
                    acc[i][j] = __builtin_amdgcn_mfma_f32_16x16x32_bf16(af[i], bfg[j], acc[i][j], 0, 0, 0);
        }
        __builtin_amdgcn_sched_barrier(0);
        __builtin_amdgcn_s_barrier();        // all waves done reading buf[cur]
    }

    // D layout: col = lane&15, row = (lane>>4)*4 + reg
    float* op = out + ((size_t)(s * N_ + n0 + wm * 64) * CO_) + o0 + wn * 32;
    #pragma unroll
    for (int i = 0; i < 4; ++i)
        #pragma unroll
        for (int j = 0; j < 2; ++j)
            #pragma unroll
            for (int r = 0; r < 4; ++r)
                op[(i * 16 + kq * 4 + r) * CO_ + j * 16 + fr] = acc[i][j][r];
}

extern "C" void kernel_launch(void* const* d_in, const int* in_sizes, int n_in,
                              void* d_out, int out_size, void* d_ws, size_t ws_size,
                              hipStream_t stream) {
    const float* x = (const float*)d_in[0];   // [S, N, CI]
    const float* W = (const float*)d_in[1];   // [K, CO, CI]

    __hip_bfloat16* winb = (__hip_bfloat16*)d_ws;                               // 2 MB
    __hip_bfloat16* Wbb  = (__hip_bfloat16*)((char*)d_ws +
                              (size_t)S_ * N_ * CI_ * sizeof(__hip_bfloat16));  // 1 MB
    float* out = (float*)d_out;               // [S, N, CO] fp32

    win_kernel<<<256, 256, 0, stream>>>(x, W, winb, Wbb);
    gemm_kernel<<<dim3(64, 4), 256, 0, stream>>>(winb, Wbb, out);
}

// Round 4
// 88.043 us; speedup vs baseline: 1.1155x; 1.1155x over previous
//
#include <hip/hip_runtime.h>
#include <hip/hip_bf16.h>

#define S_   8
#define N_   1024
#define KG_  16
#define MW_  64
#define CI_  128
#define CO_  256

typedef __attribute__((ext_vector_type(8))) short bf16x8;
typedef __attribute__((ext_vector_type(4))) float f32x4;

// ---------------------------------------------------------------------------
// Fused: W fp32->bf16 convert + circular sliding-window sums (bf16 out).
// win[s][t][c] = sum_{m<64} x[s][(t+m)%N][c]
// ---------------------------------------------------------------------------
__global__ __launch_bounds__(256) void win_kernel(const float* __restrict__ x,
                                                  const float* __restrict__ W,
                                                  __hip_bfloat16* __restrict__ win,
                                                  __hip_bfloat16* __restrict__ Wb) {
    __shared__ float lds[96][CI_];           // 48 KB
    const int b   = blockIdx.x;              // 0..255
    const int tid = threadIdx.x;

    // --- W conversion: 8 elems per thread ---
    {
        const int wi = (b * 256 + tid) * 8;
        const float4 v0 = *(const float4*)&W[wi];
        const float4 v1 = *(const float4*)&W[wi + 4];
        union { unsigned short u[8]; uint4 v; } o;
        __hip_bfloat16 h;
        h = __float2bfloat16(v0.x); o.u[0] = *(unsigned short*)&h;
        h = __float2bfloat16(v0.y); o.u[1] = *(unsigned short*)&h;
        h = __float2bfloat16(v0.z); o.u[2] = *(unsigned short*)&h;
        h = __float2bfloat16(v0.w); o.u[3] = *(unsigned short*)&h;
        h = __float2bfloat16(v1.x); o.u[4] = *(unsigned short*)&h;
        h = __float2bfloat16(v1.y); o.u[5] = *(unsigned short*)&h;
        h = __float2bfloat16(v1.z); o.u[6] = *(unsigned short*)&h;
        h = __float2bfloat16(v1.w); o.u[7] = *(unsigned short*)&h;
        *(uint4*)&Wb[wi] = o.v;
    }

    // --- sliding window ---
    const int s   = b >> 5;
    const int t0  = (b & 31) << 5;           // 32 t's per block
    const float* xs = x + (size_t)s * N_ * CI_;

    for (int e = tid * 4; e < 96 * CI_; e += 256 * 4) {
        const int r = e >> 7;
        const int c = e & (CI_ - 1);
        *(float4*)&lds[r][c] = *(const float4*)&xs[((t0 + r) & (N_ - 1)) * CI_ + c];
    }
    __syncthreads();

    const int c  = tid & (CI_ - 1);
    const int tb = (tid >> 7) << 4;          // 0 or 16
    float s0 = 0.f, s1 = 0.f, s2 = 0.f, s3 = 0.f;
    #pragma unroll
    for (int m = 0; m < MW_; m += 4) {
        s0 += lds[tb + m + 0][c];
        s1 += lds[tb + m + 1][c];
        s2 += lds[tb + m + 2][c];
        s3 += lds[tb + m + 3][c];
    }
    float w = (s0 + s1) + (s2 + s3);
    __hip_bfloat16* wo = win + (size_t)s * N_ * CI_;
    wo[(t0 + tb) * CI_ + c] = __float2bfloat16(w);
    #pragma unroll
    for (int t = 1; t < 16; ++t) {
        w += lds[tb + t - 1 + MW_][c] - lds[tb + t - 1][c];
        wo[(t0 + tb + t) * CI_ + c] = __float2bfloat16(w);
    }
}

// ---------------------------------------------------------------------------
// out[s,n,o] = sum_{g,c} win[s,(n+64g)%N,c] * W[g,o,c]
// MFMA GEMM, M=8192, N=256, K=2048.
// Tile 64x64, BK=64, grid (128,4)=512 blocks => 2 blocks/CU (TLP between
// blocks hides ds_read / vmcnt / L3 latency; barriers are per-block).
// 4 waves, wave tile 32x32 (2x2 frags of 16x16x32 bf16).
// LDS 32 KB double-buffered; counted vmcnt(4) keeps next tile in flight.
// Swizzle: 128B row = 8 x 16B slots, phys slot = logical ^ (row&7), applied
// identically on pre-swizzled global source and on ds_read (involution).
// ---------------------------------------------------------------------------
#define BKE  64                 // K elems per step
#define AST  (64 * BKE)         // 4096 elems = 8 KB
#define BST  (64 * BKE)         // 4096 elems = 8 KB
#define KSTEPS 32

__global__ __launch_bounds__(256, 2) void gemm_kernel(const __hip_bfloat16* __restrict__ winb,
                                                      const __hip_bfloat16* __restrict__ Wb,
                                                      float* __restrict__ out) {
    __shared__ __align__(16) unsigned short Alds[2 * AST];   // 16 KB
    __shared__ __align__(16) unsigned short Blds[2 * BST];   // 16 KB

    const int tid = threadIdx.x;
    const int l   = tid & 63;
    const int wv  = tid >> 6;
    const int s   = blockIdx.x >> 4;         // 0..7
    const int n0  = (blockIdx.x & 15) << 6;  // 64-row tile
    const int o0  = blockIdx.y << 6;         // 64-col tile

    const int wm = wv >> 1;                  // 0..1: 32-row half
    const int wn = wv & 1;                   // 0..1: 32-col half
    const int fr = l & 15;
    const int kq = l >> 4;                   // 0..3
    const int rl = l >> 3;                   // staging: row within 8-row chunk
    const int ps = l & 7;                    // staging: physical 16B slot

    const unsigned short* winp = (const unsigned short*)winb + (size_t)s * N_ * CI_;
    const unsigned short* Wp   = (const unsigned short*)Wb;

    f32x4 acc[2][2];
    #pragma unroll
    for (int i = 0; i < 2; ++i)
        #pragma unroll
        for (int j = 0; j < 2; ++j)
            acc[i][j] = f32x4{0.f, 0.f, 0.f, 0.f};

    // Stage tile t into buffer buf: A 8 chunks of 1KB, B 8 chunks; 4/wave.
    auto stage = [&](int t, int buf) {
        const int g  = t >> 1;
        const int ch = (t & 1) << 6;         // K half within the group
        unsigned short* Ab = &Alds[buf * AST];
        unsigned short* Bb = &Blds[buf * BST];
        #pragma unroll
        for (int q = 0; q < 2; ++q) {
            const int rb  = (wv * 2 + q) * 8;
            const int row = rb + rl;
            const int ss  = ps ^ (row & 7);
            const unsigned short* src =
                winp + (((n0 + (g << 6) + row) & (N_ - 1)) * CI_) + ch + ss * 8;
            __builtin_amdgcn_global_load_lds((const __attribute__((address_space(1))) void*)src,
                                             (__attribute__((address_space(3))) void*)(Ab + rb * BKE),
                                             16, 0, 0);
        }
        #pragma unroll
        for (int q = 0; q < 2; ++q) {
            const int rb  = (wv * 2 + q) * 8;
            const int row = rb + rl;         // o index within tile
            const int ss  = ps ^ (row & 7);
            const unsigned short* src =
                Wp + ((g * CO_ + o0 + row) * CI_) + ch + ss * 8;
            __builtin_amdgcn_global_load_lds((const __attribute__((address_space(1))) void*)src,
                                             (__attribute__((address_space(3))) void*)(Bb + rb * BKE),
                                             16, 0, 0);
        }
    };

    stage(0, 0);                             // 4 loads in flight

    for (int t = 0; t < KSTEPS; ++t) {
        const int cur = t & 1;
        if (t < KSTEPS - 1) {
            stage(t + 1, cur ^ 1);           // +4 -> 8 in flight
            asm volatile("s_waitcnt vmcnt(4)" ::: "memory");   // tile t done
        } else {
            asm volatile("s_waitcnt vmcnt(0)" ::: "memory");
        }
        __builtin_amdgcn_sched_barrier(0);
        __builtin_amdgcn_s_barrier();        // buf[cur] ready for all waves

        const unsigned short* Ab = &Alds[cur * AST];
        const unsigned short* Bb = &Blds[cur * BST];
        #pragma unroll
        for (int ks = 0; ks < 2; ++ks) {
            const int sl = ks * 4 + kq;      // logical 16B slot 0..7
            bf16x8 af[2], bfg[2];
            #pragma unroll
            for (int i = 0; i < 2; ++i) {
                const int row = wm * 32 + i * 16 + fr;
                af[i] = *(const bf16x8*)&Ab[row * BKE + ((sl ^ (row & 7)) * 8)];
            }
            #pragma unroll
            for (int j = 0; j < 2; ++j) {
                const int col = wn * 32 + j * 16 + fr;
                bfg[j] = *(const bf16x8*)&Bb[col * BKE + ((sl ^ (col & 7)) * 8)];
            }
            #pragma unroll
            for (int i = 0; i < 2; ++i)
                #pragma unroll
                for (int j = 0; j < 2; ++j)
                    acc[i][j] = __builtin_amdgcn_mfma_f32_16x16x32_bf16(af[i], bfg[j], acc[i][j], 0, 0, 0);
        }
        __builtin_amdgcn_sched_barrier(0);
        __builtin_amdgcn_s_barrier();        // all waves done reading buf[cur]
    }

    // D layout: col = lane&15, row = (lane>>4)*4 + reg
    float* op = out + ((size_t)(s * N_ + n0 + wm * 32) * CO_) + o0 + wn * 32;
    #pragma unroll
    for (int i = 0; i < 2; ++i)
        #pragma unroll
        for (int j = 0; j < 2; ++j)
            #pragma unroll
            for (int r = 0; r < 4; ++r)
                op[(i * 16 + kq * 4 + r) * CO_ + j * 16 + fr] = acc[i][j][r];
}

extern "C" void kernel_launch(void* const* d_in, const int* in_sizes, int n_in,
                              void* d_out, int out_size, void* d_ws, size_t ws_size,
                              hipStream_t stream) {
    const float* x = (const float*)d_in[0];   // [S, N, CI]
    const float* W = (const float*)d_in[1];   // [K, CO, CI]

    __hip_bfloat16* winb = (__hip_bfloat16*)d_ws;                               // 2 MB
    __hip_bfloat16* Wbb  = (__hip_bfloat16*)((char*)d_ws +
                              (size_t)S_ * N_ * CI_ * sizeof(__hip_bfloat16));  // 1 MB
    float* out = (float*)d_out;               // [S, N, CO] fp32

    win_kernel<<<256, 256, 0, stream>>>(x, W, winb, Wbb);
    gemm_kernel<<<dim3(128, 4), 256, 0, stream>>>(winb, Wbb, out);
}

// Round 5
// 87.594 us; speedup vs baseline: 1.1212x; 1.0051x over previous
//
#include <hip/hip_runtime.h>
#include <hip/hip_bf16.h>

#define S_   8
#define N_   1024
#define KG_  16
#define MW_  64
#define CI_  128
#define CO_  256

typedef __attribute__((ext_vector_type(8))) short bf16x8;
typedef __attribute__((ext_vector_type(4))) float f32x4;

// ---------------------------------------------------------------------------
// Fused: W fp32->bf16 convert + circular sliding-window sums (bf16 out).
// win[s][t][c] = sum_{m<64} x[s][(t+m)%N][c]
// ---------------------------------------------------------------------------
__global__ __launch_bounds__(256) void win_kernel(const float* __restrict__ x,
                                                  const float* __restrict__ W,
                                                  __hip_bfloat16* __restrict__ win,
                                                  __hip_bfloat16* __restrict__ Wb) {
    __shared__ float lds[96][CI_];           // 48 KB
    const int b   = blockIdx.x;              // 0..255
    const int tid = threadIdx.x;

    // --- W conversion: 8 elems per thread ---
    {
        const int wi = (b * 256 + tid) * 8;
        const float4 v0 = *(const float4*)&W[wi];
        const float4 v1 = *(const float4*)&W[wi + 4];
        union { unsigned short u[8]; uint4 v; } o;
        __hip_bfloat16 h;
        h = __float2bfloat16(v0.x); o.u[0] = *(unsigned short*)&h;
        h = __float2bfloat16(v0.y); o.u[1] = *(unsigned short*)&h;
        h = __float2bfloat16(v0.z); o.u[2] = *(unsigned short*)&h;
        h = __float2bfloat16(v0.w); o.u[3] = *(unsigned short*)&h;
        h = __float2bfloat16(v1.x); o.u[4] = *(unsigned short*)&h;
        h = __float2bfloat16(v1.y); o.u[5] = *(unsigned short*)&h;
        h = __float2bfloat16(v1.z); o.u[6] = *(unsigned short*)&h;
        h = __float2bfloat16(v1.w); o.u[7] = *(unsigned short*)&h;
        *(uint4*)&Wb[wi] = o.v;
    }

    // --- sliding window ---
    const int s   = b >> 5;
    const int t0  = (b & 31) << 5;           // 32 t's per block
    const float* xs = x + (size_t)s * N_ * CI_;

    for (int e = tid * 4; e < 96 * CI_; e += 256 * 4) {
        const int r = e >> 7;
        const int c = e & (CI_ - 1);
        *(float4*)&lds[r][c] = *(const float4*)&xs[((t0 + r) & (N_ - 1)) * CI_ + c];
    }
    __syncthreads();

    const int c  = tid & (CI_ - 1);
    const int tb = (tid >> 7) << 4;          // 0 or 16
    float s0 = 0.f, s1 = 0.f, s2 = 0.f, s3 = 0.f;
    #pragma unroll
    for (int m = 0; m < MW_; m += 4) {
        s0 += lds[tb + m + 0][c];
        s1 += lds[tb + m + 1][c];
        s2 += lds[tb + m + 2][c];
        s3 += lds[tb + m + 3][c];
    }
    float w = (s0 + s1) + (s2 + s3);
    __hip_bfloat16* wo = win + (size_t)s * N_ * CI_;
    wo[(t0 + tb) * CI_ + c] = __float2bfloat16(w);
    #pragma unroll
    for (int t = 1; t < 16; ++t) {
        w += lds[tb + t - 1 + MW_][c] - lds[tb + t - 1][c];
        wo[(t0 + tb + t) * CI_ + c] = __float2bfloat16(w);
    }
}

// ---------------------------------------------------------------------------
// out[s,n,o] = sum_{g,c} win[s,(n+64g)%N,c] * W[g,o,c]
// MFMA GEMM, M=8192, N=256, K=2048.  Tile 64x64, BK=64, 512 blocks.
// XCD pinning: s = blockIdx.x & 7 (round-robin block->XCD) so each XCD's 64
// blocks share one 1.25 MB working set (win[s] 256KB + W 1MB) -> local L2.
// Triple-buffered LDS (48 KB), 2 blocks/CU, counted vmcnt(8): 2 tiles in
// flight, ~2 K-steps of latency cover.
// Swizzle: 128B row = 8 x 16B slots, phys slot = logical ^ (row&7), applied
// on pre-swizzled global source and on ds_read (involution).
// ---------------------------------------------------------------------------
#define BKE  64                 // K elems per step
#define AST  (64 * BKE)         // 4096 elems = 8 KB
#define BST  (64 * BKE)         // 4096 elems = 8 KB
#define KSTEPS 32

__global__ __launch_bounds__(256, 2) void gemm_kernel(const __hip_bfloat16* __restrict__ winb,
                                                      const __hip_bfloat16* __restrict__ Wb,
                                                      float* __restrict__ out) {
    __shared__ __align__(16) unsigned short Alds[3 * AST];   // 24 KB
    __shared__ __align__(16) unsigned short Blds[3 * BST];   // 24 KB

    const int tid = threadIdx.x;
    const int l   = tid & 63;
    const int wv  = tid >> 6;
    const int s   = blockIdx.x & 7;          // XCD-pinned sample index
    const int rem = blockIdx.x >> 3;         // 0..63
    const int n0  = (rem & 15) << 6;         // 64-row tile
    const int o0  = (rem >> 4) << 6;         // 64-col tile

    const int wm = wv >> 1;                  // 0..1: 32-row half
    const int wn = wv & 1;                   // 0..1: 32-col half
    const int fr = l & 15;
    const int kq = l >> 4;                   // 0..3
    const int rl = l >> 3;                   // staging: row within 8-row chunk
    const int ps = l & 7;                    // staging: physical 16B slot

    const unsigned short* winp = (const unsigned short*)winb + (size_t)s * N_ * CI_;
    const unsigned short* Wp   = (const unsigned short*)Wb;

    f32x4 acc[2][2];
    #pragma unroll
    for (int i = 0; i < 2; ++i)
        #pragma unroll
        for (int j = 0; j < 2; ++j)
            acc[i][j] = f32x4{0.f, 0.f, 0.f, 0.f};

    // Stage tile t: A 8 chunks of 1KB, B 8 chunks; 4 global_load_lds per wave.
    auto stage = [&](int t, unsigned short* Ab, unsigned short* Bb) {
        const int g  = t >> 1;
        const int ch = (t & 1) << 6;         // K half within the group
        #pragma unroll
        for (int q = 0; q < 2; ++q) {
            const int rb  = (wv * 2 + q) * 8;
            const int row = rb + rl;
            const int ss  = ps ^ (row & 7);
            const unsigned short* src =
                winp + (((n0 + (g << 6) + row) & (N_ - 1)) * CI_) + ch + ss * 8;
            __builtin_amdgcn_global_load_lds((const __attribute__((address_space(1))) void*)src,
                                             (__attribute__((address_space(3))) void*)(Ab + rb * BKE),
                                             16, 0, 0);
        }
        #pragma unroll
        for (int q = 0; q < 2; ++q) {
            const int rb  = (wv * 2 + q) * 8;
            const int row = rb + rl;         // o index within tile
            const int ss  = ps ^ (row & 7);
            const unsigned short* src =
                Wp + ((g * CO_ + o0 + row) * CI_) + ch + ss * 8;
            __builtin_amdgcn_global_load_lds((const __attribute__((address_space(1))) void*)src,
                                             (__attribute__((address_space(3))) void*)(Bb + rb * BKE),
                                             16, 0, 0);
        }
    };

    stage(0, Alds,       Blds);              // 4 in flight
    stage(1, Alds + AST, Blds + BST);        // 8 in flight

    int cb = 0;                              // buffer holding tile t
    int sb = 2;                              // buffer to stage tile t+2 into

    for (int t = 0; t < KSTEPS; ++t) {
        if (t + 2 < KSTEPS) {
            stage(t + 2, Alds + sb * AST, Blds + sb * BST);   // 12 in flight
            asm volatile("s_waitcnt vmcnt(8)" ::: "memory");  // tile t done
        } else if (t == KSTEPS - 2) {
            asm volatile("s_waitcnt vmcnt(4)" ::: "memory");
        } else {
            asm volatile("s_waitcnt vmcnt(0)" ::: "memory");
        }
        __builtin_amdgcn_sched_barrier(0);
        __builtin_amdgcn_s_barrier();        // buf[cb] ready for all waves

        const unsigned short* Ab = Alds + cb * AST;
        const unsigned short* Bb = Blds + cb * BST;
        #pragma unroll
        for (int ks = 0; ks < 2; ++ks) {
            const int sl = ks * 4 + kq;      // logical 16B slot 0..7
            bf16x8 af[2], bfg[2];
            #pragma unroll
            for (int i = 0; i < 2; ++i) {
                const int row = wm * 32 + i * 16 + fr;
                af[i] = *(const bf16x8*)&Ab[row * BKE + ((sl ^ (row & 7)) * 8)];
            }
            #pragma unroll
            for (int j = 0; j < 2; ++j) {
                const int col = wn * 32 + j * 16 + fr;
                bfg[j] = *(const bf16x8*)&Bb[col * BKE + ((sl ^ (col & 7)) * 8)];
            }
            #pragma unroll
            for (int i = 0; i < 2; ++i)
                #pragma unroll
                for (int j = 0; j < 2; ++j)
                    acc[i][j] = __builtin_amdgcn_mfma_f32_16x16x32_bf16(af[i], bfg[j], acc[i][j], 0, 0, 0);
        }
        __builtin_amdgcn_sched_barrier(0);
        __builtin_amdgcn_s_barrier();        // all waves done reading buf[cb]

        cb = (cb == 2) ? 0 : cb + 1;
        sb = (sb == 2) ? 0 : sb + 1;
    }

    // D layout: col = lane&15, row = (lane>>4)*4 + reg
    float* op = out + ((size_t)(s * N_ + n0 + wm * 32) * CO_) + o0 + wn * 32;
    #pragma unroll
    for (int i = 0; i < 2; ++i)
        #pragma unroll
        for (int j = 0; j < 2; ++j)
            #pragma unroll
            for (int r = 0; r < 4; ++r)
                op[(i * 16 + kq * 4 + r) * CO_ + j * 16 + fr] = acc[i][j][r];
}

extern "C" void kernel_launch(void* const* d_in, const int* in_sizes, int n_in,
                              void* d_out, int out_size, void* d_ws, size_t ws_size,
                              hipStream_t stream) {
    const float* x = (const float*)d_in[0];   // [S, N, CI]
    const float* W = (const float*)d_in[1];   // [K, CO, CI]

    __hip_bfloat16* winb = (__hip_bfloat16*)d_ws;                               // 2 MB
    __hip_bfloat16* Wbb  = (__hip_bfloat16*)((char*)d_ws +
                              (size_t)S_ * N_ * CI_ * sizeof(__hip_bfloat16));  // 1 MB
    float* out = (float*)d_out;               // [S, N, CO] fp32

    win_kernel<<<256, 256, 0, stream>>>(x, W, winb, Wbb);
    gemm_kernel<<<512, 256, 0, stream>>>(winb, Wbb, out);
}